// Round 1
// baseline (523.881 us; speedup 1.0000x reference)
//
#include <hip/hip_runtime.h>
#include <math.h>

// Problem constants (from reference): x (16,256,128,128) f32, attr (16,64) f32,
// w_emb (256,) f32. out (16,256,128,128) f32.
#define B_  16
#define C_  256
#define A_  64
#define HW_ 16384          // 128*128
#define HW4 (HW_ / 4)      // 4096 float4 per (b, c) plane row

// ---------------------------------------------------------------------------
// K1: y[b,n] = sum_c w_emb[c] * x[b,c,n]
// One thread per (b, n4) float4 group. Reads x exactly once (1.07 GB).
// ---------------------------------------------------------------------------
__global__ __launch_bounds__(256) void k_y(const float* __restrict__ x,
                                           const float* __restrict__ w_emb,
                                           float4* __restrict__ y) {
    __shared__ float w[C_];
    for (int i = threadIdx.x; i < C_; i += 256) w[i] = w_emb[i];
    __syncthreads();

    const int idx = blockIdx.x * 256 + threadIdx.x;   // 0 .. B_*HW4-1 (65536)
    const int n4  = idx & (HW4 - 1);
    const int b   = idx >> 12;                        // / 4096

    const float4* xp = (const float4*)(x + (size_t)b * C_ * HW_) + n4;
    float4 acc = {0.f, 0.f, 0.f, 0.f};
    #pragma unroll 8
    for (int c = 0; c < C_; ++c) {
        const float4 v = xp[(size_t)c * HW4];         // 64KB stride, coalesced across lanes
        const float wc = w[c];
        acc.x += wc * v.x; acc.y += wc * v.y;
        acc.z += wc * v.z; acc.w += wc * v.w;
    }
    y[idx] = acc;
}

// ---------------------------------------------------------------------------
// K2: s[b,n] = sum_a attr[b,a] * softmax_over_b(attr[b,a] * y[b,n])
// One thread per pixel n; computes all 16 batch entries at once.
// 256 blocks x 64 threads = 16384 threads (1 wave per CU).
// ---------------------------------------------------------------------------
__global__ __launch_bounds__(64) void k_s(const float* __restrict__ y,
                                          const float* __restrict__ attr,
                                          float* __restrict__ s) {
    __shared__ float at[B_ * A_];
    for (int i = threadIdx.x; i < B_ * A_; i += 64) at[i] = attr[i];
    __syncthreads();

    const int n = blockIdx.x * 64 + threadIdx.x;      // 0 .. HW_-1

    float yv[B_];
    #pragma unroll
    for (int b = 0; b < B_; ++b) yv[b] = y[b * HW_ + n];

    float acc[B_];
    #pragma unroll
    for (int b = 0; b < B_; ++b) acc[b] = 0.f;

    for (int a = 0; a < A_; ++a) {
        float t[B_];
        float m = -INFINITY;
        #pragma unroll
        for (int b = 0; b < B_; ++b) {
            t[b] = at[b * A_ + a] * yv[b];
            m = fmaxf(m, t[b]);
        }
        float e[B_];
        float Z = 0.f;
        #pragma unroll
        for (int b = 0; b < B_; ++b) {
            e[b] = expf(t[b] - m);
            Z += e[b];
        }
        const float invZ = 1.f / Z;
        #pragma unroll
        for (int b = 0; b < B_; ++b)
            acc[b] += at[b * A_ + a] * e[b] * invZ;
    }

    #pragma unroll
    for (int b = 0; b < B_; ++b) s[b * HW_ + n] = acc[b];
}

// ---------------------------------------------------------------------------
// K3: out[b,c,n] = w_emb[c] * s[b,n]
// One thread per (b, n4); loops over all 256 c with float4 stores.
// s read once per thread (registers); pure write-bound (1.07 GB).
// ---------------------------------------------------------------------------
__global__ __launch_bounds__(256) void k_out(const float4* __restrict__ s,
                                             const float* __restrict__ w_emb,
                                             float4* __restrict__ out) {
    __shared__ float w[C_];
    for (int i = threadIdx.x; i < C_; i += 256) w[i] = w_emb[i];
    __syncthreads();

    const int idx = blockIdx.x * 256 + threadIdx.x;   // 0 .. B_*HW4-1
    const int n4  = idx & (HW4 - 1);
    const int b   = idx >> 12;

    const float4 sv = s[idx];                         // s laid out [B_][HW_]
    const size_t base = (size_t)b * C_ * HW4 + n4;
    #pragma unroll 8
    for (int c = 0; c < C_; ++c) {
        const float wc = w[c];
        float4 o;
        o.x = wc * sv.x; o.y = wc * sv.y;
        o.z = wc * sv.z; o.w = wc * sv.w;
        out[base + (size_t)c * HW4] = o;              // coalesced 1KB/wave stores
    }
}

extern "C" void kernel_launch(void* const* d_in, const int* in_sizes, int n_in,
                              void* d_out, int out_size, void* d_ws, size_t ws_size,
                              hipStream_t stream) {
    const float* x     = (const float*)d_in[0];   // (16,256,128,128)
    const float* attr  = (const float*)d_in[1];   // (16,64)
    const float* w_emb = (const float*)d_in[2];   // (256,)
    float* out = (float*)d_out;

    // Workspace: y (B_*HW_ floats = 1 MB) then s (1 MB).
    float* y = (float*)d_ws;
    float* s = y + (size_t)B_ * HW_;

    k_y  <<<(B_ * HW4) / 256, 256, 0, stream>>>(x, w_emb, (float4*)y);
    k_s  <<<HW_ / 64,          64, 0, stream>>>(y, attr, s);
    k_out<<<(B_ * HW4) / 256, 256, 0, stream>>>((const float4*)s, w_emb, (float4*)out);
}

// Round 2
// 520.810 us; speedup vs baseline: 1.0059x; 1.0059x over previous
//
#include <hip/hip_runtime.h>
#include <math.h>

// x (16,256,128,128) f32, attr (16,64) f32, w_emb (256,) f32 -> out (16,256,128,128) f32
// Algebra: sa_t is rank-1 => y[b,n] = sum_c w[c]*x[b,c,n]; t[b,a,n] = attr[b,a]*y[b,n];
//          s[b,n] = sum_a attr[b,a]*softmax_b(t); out[b,c,n] = w[c]*s[b,n].
#define B_  16
#define C_  256
#define A_  64
#define HW_ 16384          // 128*128
#define HW4 (HW_ / 4)      // 4096
#define QSPLIT 4           // C-split factor for occupancy (4 waves/SIMD instead of 1)
#define CQ  (C_ / QSPLIT)  // 64 channels per quarter

// ---------------------------------------------------------------------------
// K1: ypart[q][b][n] = sum_{c in quarter q} w[c] * x[b,c,n]
// 1024 blocks x 256 thr (4 blocks/CU). Reads x exactly once (1.07 GB).
// ---------------------------------------------------------------------------
__global__ __launch_bounds__(256) void k_y(const float* __restrict__ x,
                                           const float* __restrict__ w_emb,
                                           float4* __restrict__ ypart) {
    const int q    = blockIdx.x >> 8;                    // 0..3 (uniform per block)
    const int idxw = ((blockIdx.x & 255) << 8) + threadIdx.x;  // 0..65535
    const int n4   = idxw & (HW4 - 1);
    const int b    = idxw >> 12;

    __shared__ float w[CQ];
    if (threadIdx.x < CQ) w[threadIdx.x] = w_emb[q * CQ + threadIdx.x];
    __syncthreads();

    const float4* xp = (const float4*)(x + (size_t)b * C_ * HW_) + (size_t)(q * CQ) * HW4 + n4;
    float4 acc = {0.f, 0.f, 0.f, 0.f};
    #pragma unroll 8
    for (int c = 0; c < CQ; ++c) {
        const float4 v = xp[(size_t)c * HW4];            // 1KB/wave coalesced
        const float wc = w[c];
        acc.x += wc * v.x; acc.y += wc * v.y;
        acc.z += wc * v.z; acc.w += wc * v.w;
    }
    ypart[(size_t)q * (B_ * HW4) + idxw] = acc;
}

// ---------------------------------------------------------------------------
// K2: s[b,n] = sum_a attr[b,a] * softmax_over_b(attr[b,a] * y[b,n]),
//     where y[b,n] = sum_q ypart[q][b][n].  One thread per pixel (all 16 b).
// 64 blocks x 256 thr. ~5 MB traffic + 16.8M exp -> ~10 us.
// ---------------------------------------------------------------------------
__global__ __launch_bounds__(256) void k_s(const float* __restrict__ ypart,
                                           const float* __restrict__ attr,
                                           float* __restrict__ s) {
    __shared__ float at[B_ * A_];
    for (int i = threadIdx.x; i < B_ * A_; i += 256) at[i] = attr[i];
    __syncthreads();

    const int n = blockIdx.x * 256 + threadIdx.x;        // 0..HW_-1

    float yv[B_];
    #pragma unroll
    for (int b = 0; b < B_; ++b) {
        float v = 0.f;
        #pragma unroll
        for (int qq = 0; qq < QSPLIT; ++qq)
            v += ypart[(size_t)qq * (B_ * HW_) + b * HW_ + n];
        yv[b] = v;
    }

    float acc[B_];
    #pragma unroll
    for (int b = 0; b < B_; ++b) acc[b] = 0.f;

    for (int a = 0; a < A_; ++a) {
        float t[B_];
        float m = -INFINITY;
        #pragma unroll
        for (int b = 0; b < B_; ++b) {
            t[b] = at[b * A_ + a] * yv[b];
            m = fmaxf(m, t[b]);
        }
        float Z = 0.f;
        float e[B_];
        #pragma unroll
        for (int b = 0; b < B_; ++b) {
            e[b] = __expf(t[b] - m);
            Z += e[b];
        }
        const float invZ = 1.f / Z;
        #pragma unroll
        for (int b = 0; b < B_; ++b)
            acc[b] += at[b * A_ + a] * e[b] * invZ;
    }

    #pragma unroll
    for (int b = 0; b < B_; ++b) s[b * HW_ + n] = acc[b];
}

// ---------------------------------------------------------------------------
// K3: out[b,c,n] = w[c] * s[b,n], each thread owns one (b, n4) and a 64-channel
// quarter. 1024 blocks x 256 thr. Pure write-bound (1.07 GB + 4 MB s re-reads).
// ---------------------------------------------------------------------------
__global__ __launch_bounds__(256) void k_out(const float4* __restrict__ s,
                                             const float* __restrict__ w_emb,
                                             float4* __restrict__ out) {
    const int q    = blockIdx.x >> 8;
    const int idxw = ((blockIdx.x & 255) << 8) + threadIdx.x;
    const int n4   = idxw & (HW4 - 1);
    const int b    = idxw >> 12;

    __shared__ float w[CQ];
    if (threadIdx.x < CQ) w[threadIdx.x] = w_emb[q * CQ + threadIdx.x];
    __syncthreads();

    const float4 sv = s[idxw];
    float4* op = out + (size_t)b * C_ * HW4 + (size_t)(q * CQ) * HW4 + n4;
    #pragma unroll 8
    for (int c = 0; c < CQ; ++c) {
        const float wc = w[c];
        float4 o;
        o.x = wc * sv.x; o.y = wc * sv.y;
        o.z = wc * sv.z; o.w = wc * sv.w;
        op[(size_t)c * HW4] = o;
    }
}

extern "C" void kernel_launch(void* const* d_in, const int* in_sizes, int n_in,
                              void* d_out, int out_size, void* d_ws, size_t ws_size,
                              hipStream_t stream) {
    const float* x     = (const float*)d_in[0];
    const float* attr  = (const float*)d_in[1];
    const float* w_emb = (const float*)d_in[2];
    float* out = (float*)d_out;

    // ws: ypart (QSPLIT * B_ * HW_ floats = 4 MB) then s (1 MB)
    float* ypart = (float*)d_ws;
    float* s     = ypart + (size_t)QSPLIT * B_ * HW_;

    k_y  <<<QSPLIT * 256, 256, 0, stream>>>(x, w_emb, (float4*)ypart);
    k_s  <<<HW_ / 256,    256, 0, stream>>>(ypart, attr, s);
    k_out<<<QSPLIT * 256, 256, 0, stream>>>((const float4*)s, w_emb, (float4*)out);
}

// Round 3
// 435.953 us; speedup vs baseline: 1.2017x; 1.1946x over previous
//
#include <hip/hip_runtime.h>
#include <math.h>

// x (16,256,128,128) f32 = 268 MB, attr (16,64) f32, w_emb (256,) f32
// out (16,256,128,128) f32 = 268 MB.
// Rank-1 collapse: y[b,n] = sum_c w[c]*x[b,c,n];  s[b,n] = sum_a attr[b,a] *
// softmax_over_b(attr[b,a]*y[b,n]);  out[b,c,n] = w[c]*s[b,n].
// Softmax couples only across b at FIXED pixel n -> fully fusable per-pixel.
#define B_  16
#define C_  256
#define A_  64
#define HW_ 16384          // 128*128
#define P_  64             // pixels per block (lane == pixel)

__global__ __launch_bounds__(256) void k_fused(const float* __restrict__ x,
                                               const float* __restrict__ attr,
                                               const float* __restrict__ w_emb,
                                               float* __restrict__ out) {
    __shared__ float w[C_];              // 1 KB
    __shared__ float at[B_ * A_];        // 4 KB
    __shared__ float y[B_][P_];          // 4 KB
    __shared__ float part[4][B_][P_];    // 16 KB
    __shared__ float s[B_][P_];          // 4 KB

    const int t    = threadIdx.x;
    const int lane = t & 63;             // pixel within block tile
    const int wv   = t >> 6;             // wave 0..3
    const int n0   = blockIdx.x * P_;

    if (t < C_) w[t] = w_emb[t];
    for (int i = t; i < B_ * A_; i += 256) at[i] = attr[i];
    __syncthreads();

    // ---- Phase 1: y[b][px] = sum_c w[c]*x[b,c,n0+px]. Wave wv owns b=4wv..4wv+3.
    // 4 independent b-streams x unroll 4 -> 16 loads in flight (Little's law ok).
    {
        const float* xp = x + (size_t)(wv * 4) * C_ * HW_ + n0 + lane;
        float acc[4] = {0.f, 0.f, 0.f, 0.f};
        #pragma unroll 4
        for (int c = 0; c < C_; ++c) {
            const float wc = w[c];
            #pragma unroll
            for (int bb = 0; bb < 4; ++bb)
                acc[bb] += wc * __builtin_nontemporal_load(
                    xp + (size_t)bb * C_ * HW_ + (size_t)c * HW_);
        }
        #pragma unroll
        for (int bb = 0; bb < 4; ++bb) y[wv * 4 + bb][lane] = acc[bb];
    }
    __syncthreads();

    // ---- Phase 2: softmax over b per (a, pixel); wave wv handles a in [16wv,16wv+16).
    {
        float yv[B_];
        #pragma unroll
        for (int b = 0; b < B_; ++b) yv[b] = y[b][lane];
        float pacc[B_];
        #pragma unroll
        for (int b = 0; b < B_; ++b) pacc[b] = 0.f;

        for (int aa = 0; aa < 16; ++aa) {
            const int a = wv * 16 + aa;
            float tb[B_];
            float m = -INFINITY;
            #pragma unroll
            for (int b = 0; b < B_; ++b) {
                tb[b] = at[b * A_ + a] * yv[b];
                m = fmaxf(m, tb[b]);
            }
            float e[B_];
            float Z = 0.f;
            #pragma unroll
            for (int b = 0; b < B_; ++b) {
                e[b] = __expf(tb[b] - m);
                Z += e[b];
            }
            const float iZ = 1.f / Z;
            #pragma unroll
            for (int b = 0; b < B_; ++b)
                pacc[b] += at[b * A_ + a] * e[b] * iZ;
        }
        #pragma unroll
        for (int b = 0; b < B_; ++b) part[wv][b][lane] = pacc[b];
    }
    __syncthreads();

    for (int i = t; i < B_ * P_; i += 256) {
        const int b = i >> 6, px = i & 63;
        s[b][px] = part[0][b][px] + part[1][b][px] + part[2][b][px] + part[3][b][px];
    }
    __syncthreads();

    // ---- Phase 3: out[b,c,n0+px] = w[c]*s[b][px]. Wave wv owns b=4wv..4wv+3.
    #pragma unroll
    for (int bb = 0; bb < 4; ++bb) {
        const int b = wv * 4 + bb;
        const float sv = s[b][lane];
        float* op = out + (size_t)b * C_ * HW_ + n0 + lane;
        #pragma unroll 8
        for (int c = 0; c < C_; ++c)
            __builtin_nontemporal_store(w[c] * sv, op + (size_t)c * HW_);
    }
}

extern "C" void kernel_launch(void* const* d_in, const int* in_sizes, int n_in,
                              void* d_out, int out_size, void* d_ws, size_t ws_size,
                              hipStream_t stream) {
    const float* x     = (const float*)d_in[0];
    const float* attr  = (const float*)d_in[1];
    const float* w_emb = (const float*)d_in[2];
    float* out = (float*)d_out;

    k_fused<<<HW_ / P_, 256, 0, stream>>>(x, attr, w_emb, out);
}